// Round 16
// baseline (660.181 us; speedup 1.0000x reference)
//
#include <hip/hip_runtime.h>
#include <hip/hip_bf16.h>
#include <math.h>
#include <stdint.h>

#define S    256
#define GN   128

typedef __attribute__((ext_vector_type(8))) short  short8;   // 8 bf16
typedef __attribute__((ext_vector_type(4))) float  floatx4;  // MFMA C/D
typedef __attribute__((ext_vector_type(2))) float  float2v;  // v_pk_*_f32 pair

// workspace layout (bytes)
#define WS_BHI 0          // ushort[4*4*64*8] = 16384 B  (f_w2 bf16, frag order)
#define WS_RW1 16384      // ushort[2*4*64*8] =  8192 B  (r_w1 bf16, frag order)
#define WS_B2S 24576      // float  (b2.s_w + s_b)
#define WS_WS2 24592      // float[128]  (W2 @ s_w, fp32)
#define WS_W1P 25104      // float[64*8] pair-interleaved layer-1 = 2048 B
#define WS_W2E 27152      // ushort[2*64*8] = 2048 B (r_w2^T bf16, A-frag order)

__device__ __forceinline__ unsigned short bf16_rtne(float f) {
    uint32_t u = __builtin_bit_cast(uint32_t, f);
    uint32_t r = (u + 0x7fffu + ((u >> 16) & 1u)) >> 16;
    return (unsigned short)r;
}
__device__ __forceinline__ uint32_t cvt_pk_bf16(float a, float b) {
    float2 hh; hh.x = a; hh.y = b;
    __hip_bfloat162 pk = __float22bfloat162_rn(hh);   // v_cvt_pk_bf16_f32
    uint32_t u; __builtin_memcpy(&u, &pk, 4);
    return u;
}

// ---------- pre-pack kernel: weights -> bf16 in MFMA fragment order ----------
__global__ __launch_bounds__(256)
void nerf_prep(const float* __restrict__ f_w1, const float* __restrict__ f_b1,
               const float* __restrict__ f_w2, const float* __restrict__ f_b2,
               const float* __restrict__ s_w,  const float* __restrict__ s_b,
               const float* __restrict__ r_w1, const float* __restrict__ r_w2,
               unsigned char* __restrict__ ws)
{
    const int tid = threadIdx.x;
    if (tid < 128) {                       // ws2 = W2 @ s_w  (fp32) -> global
        float acc = 0.0f;
        for (int n = 0; n < 64; ++n) acc += f_w2[tid * 64 + n] * s_w[n];
        ((float*)(ws + WS_WS2))[tid] = acc;
    } else if (tid == 128) {               // b2s = b2 . s_w + s_b
        float acc = s_b[0];
        for (int n = 0; n < 64; ++n) acc += f_b2[n] * s_w[n];
        *(float*)(ws + WS_B2S) = acc;
    }
    // layer-1 pair-interleaved pack: pair pp covers k=2pp,2pp+1:
    //   {wx0,wx1, wy0,wy1, wz0,wz1, b0,b1}  (aligned float2 pairs for v_pk_fma)
    {
        float* w1pk = (float*)(ws + WS_W1P);
        for (int pp = tid; pp < 64; pp += 256) {
            int k0 = 2 * pp, k1 = 2 * pp + 1;
            w1pk[pp * 8 + 0] = f_w1[k0];       w1pk[pp * 8 + 1] = f_w1[k1];
            w1pk[pp * 8 + 2] = f_w1[128 + k0]; w1pk[pp * 8 + 3] = f_w1[128 + k1];
            w1pk[pp * 8 + 4] = f_w1[256 + k0]; w1pk[pp * 8 + 5] = f_w1[256 + k1];
            w1pk[pp * 8 + 6] = f_b1[k0];       w1pk[pp * 8 + 7] = f_b1[k1];
        }
    }

    unsigned short* bhi = (unsigned short*)(ws + WS_BHI);
    for (int i = tid; i < 8192; i += 256) {
        int j = i & 7, L = (i >> 3) & 63, g = i >> 9;   // g = kc*4 + tn
        int tn = g & 3, kc = g >> 2;
        int q = L >> 4, cc = L & 15;
        int k = kc * 32 + q * 8 + j;
        bhi[i] = bf16_rtne(f_w2[k * 64 + tn * 16 + cc]);
    }
    unsigned short* rw = (unsigned short*)(ws + WS_RW1);
    for (int i = tid; i < 4096; i += 256) {
        int j = i & 7, L = (i >> 3) & 63, g = i >> 9;   // g = ks*4 + tn
        int tn = g & 3, ks = g >> 2;
        int q = L >> 4, cc = L & 15;
        int k = ks * 32 + q * 8 + j;
        rw[i] = bf16_rtne(r_w1[k * 64 + tn * 16 + cc]);
    }
    // r_w2^T in A-fragment order for the phase-E MFMA:
    // A[row=out-channel][k=hidden]; rows 3..15 zero.
    unsigned short* w2e = (unsigned short*)(ws + WS_W2E);
    for (int i = tid; i < 1024; i += 256) {
        int j = i & 7, L = (i >> 3) & 63, kf = i >> 9;
        int q = L >> 4, ch = L & 15;
        int k = kf * 32 + q * 8 + j;
        w2e[i] = (ch < 3) ? bf16_rtne(r_w2[k * 3 + ch]) : (unsigned short)0;
    }
}

// ---------------------------- main kernel -----------------------------------
// R16 = R15 with deeper pipelining (R15 proved dependency stalls are the live
// margin: unroll-2 was the only post-R12 change that moved time):
//  - kc loop fully unrolled (VGPR headroom: R15 used 64 of the 128 budget,
//    LDS is the binding occupancy cap)
//  - phase-D ph loop unroll 2 (disjoint rows: pass-0 writes 0-31, pass-1
//    reads 32-63; both passes' afr/rb loads issue together)
//  - hd[] uniform loads hoisted above the scan
// Spill tripwire: WRITE_SIZE must stay ~8.3 MB.
__global__ __launch_bounds__(256, 4)
void nerf_mfma(const float* __restrict__ rays_o,
               const float* __restrict__ rays_d,
               const float* __restrict__ grid,
               const float* __restrict__ f_b2,
               const float* __restrict__ r_w1,
               const float* __restrict__ r_b1,
               const float* __restrict__ r_b2,
               const unsigned char* __restrict__ ws,
               float* __restrict__ out)
{
    // fh: bf16 [256 rows][64], XOR-swizzled in 8-ushort groups: conflict-free b128
    __shared__ unsigned short fh[256 * 64];
    __shared__ float w1p[512];            // pair-interleaved layer-1
    __shared__ float ws2L[128];           // W2 @ s_w (fp32)
    __shared__ float aLds[S];             // life 1: alpha for scan; life 2: weight*mask2
    __shared__ float maskLds[S];
    __shared__ float distLds[S];
    __shared__ float sWaveSum[4];
    __shared__ float sPart[4][3];

    const int tid   = threadIdx.x;
    const int ray   = blockIdx.x;
    const int lane  = tid & 63;
    const int wv    = tid >> 6;
    const int q     = lane >> 4;
    const int c     = lane & 15;
    const int mbase = wv * 64;

    // stage layer-1 pack (2 KB) + ws2 (512 B) into LDS
    if (tid < 128) {
        ((float4*)w1p)[tid] = ((const float4*)(ws + WS_W1P))[tid];
        ws2L[tid] = ((const float*)(ws + WS_WS2))[tid];
    }

    // ---------------- Phase A: geometry + grid sample (thread = sample) ------
    const float stop = 1.0f - 1.0f / (float)(S + 2);
    const float step = stop / (float)S;
    float u0 = (float)tid * step;
    float u1 = (float)(tid + 1) * step;
    float t    = (u0 < 0.5f) ? 2.0f * u0 : 1.0f / (2.0f - 2.0f * u0);
    float tn_  = (u1 < 0.5f) ? 2.0f * u1 : 1.0f / (2.0f - 2.0f * u1);
    float dist = tn_ - t;

    float ox = rays_o[ray * 3 + 0], oy = rays_o[ray * 3 + 1], oz = rays_o[ray * 3 + 2];
    float dxv = rays_d[ray * 3 + 0], dyv = rays_d[ray * 3 + 1], dzv = rays_d[ray * 3 + 2];

    float px = ox + dxv * t, py = oy + dyv * t, pz = oz + dzv * t;
    float nrm = sqrtf(px * px + py * py + pz * pz);
    float scale = (nrm <= 1.0f) ? 0.5f : (2.0f - 1.0f / nrm) / nrm * 0.5f;
    float cx = px * scale, cy = py * scale, cz = pz * scale;

    float ix = ((cx + 1.0f) * (float)GN - 1.0f) * 0.5f;
    float iy = ((cy + 1.0f) * (float)GN - 1.0f) * 0.5f;
    float iz = ((cz + 1.0f) * (float)GN - 1.0f) * 0.5f;
    float fx0 = floorf(ix), fy0 = floorf(iy), fz0 = floorf(iz);
    float fx = ix - fx0, fy = iy - fy0, fz = iz - fz0;
    int x0 = (int)fx0, y0 = (int)fy0, z0 = (int)fz0;

    float occ = 0.0f;
    #pragma unroll
    for (int dzc = 0; dzc < 2; ++dzc)
    #pragma unroll
    for (int dyc = 0; dyc < 2; ++dyc)
    #pragma unroll
    for (int dxc = 0; dxc < 2; ++dxc) {
        int xc = x0 + dxc, yc = y0 + dyc, zc = z0 + dzc;
        float w = (dxc ? fx : 1.0f - fx) * (dyc ? fy : 1.0f - fy) * (dzc ? fz : 1.0f - fz);
        if (xc >= 0 && xc < GN && yc >= 0 && yc < GN && zc >= 0 && zc < GN)
            occ += w * grid[(zc * GN + yc) * GN + xc];
    }
    bool maskA = occ > 0.01f;
    maskLds[tid] = maskA ? 1.0f : 0.0f;
    distLds[tid] = dist;

    // coords of the A-fragment rows this thread covers (intra-wave broadcast)
    float cxs[4], cys[4], czs[4];
    #pragma unroll
    for (int tm = 0; tm < 4; ++tm) {
        int src = tm * 16 + c;
        cxs[tm] = __shfl(cx, src, 64);
        cys[tm] = __shfl(cy, src, 64);
        czs[tm] = __shfl(cz, src, 64);
    }
    __syncthreads();   // w1p / ws2L staged

    // ------- Phase B+C: feat GEMM in two tm-passes (acc[2][4] = 32 AGPR) -----
    const unsigned short* __restrict__ bhiP = (const unsigned short*)(ws + WS_BHI);
    float sig[4];

    #pragma unroll 1
    for (int ph = 0; ph < 2; ++ph) {
        floatx4 acc[2][4];
        {
            float b2v[4];
            #pragma unroll
            for (int tn = 0; tn < 4; ++tn) b2v[tn] = f_b2[tn * 16 + c];
            #pragma unroll
            for (int tm = 0; tm < 2; ++tm)
                #pragma unroll
                for (int tn = 0; tn < 4; ++tn) {
                    floatx4 v; v[0] = b2v[tn]; v[1] = b2v[tn]; v[2] = b2v[tn]; v[3] = b2v[tn];
                    acc[tm][tn] = v;
                }
        }
        float2v sig2[2];
        sig2[0][0] = 0.0f; sig2[0][1] = 0.0f;
        sig2[1][0] = 0.0f; sig2[1][1] = 0.0f;

        #pragma unroll
        for (int kc = 0; kc < 4; ++kc) {
            const int k0  = kc * 32 + q * 8;
            const int pp0 = kc * 16 + q * 4;
            const float4* __restrict__ w1q4 = (const float4*)&w1p[pp0 * 8];
            float ws2r[8];
            *(float4*)(ws2r)     = *(const float4*)&ws2L[k0];
            *(float4*)(ws2r + 4) = *(const float4*)&ws2L[k0 + 4];

            uint32_t packed[2][4];
            #pragma unroll
            for (int p = 0; p < 4; ++p) {
                float4 q0 = w1q4[2 * p];         // {wx0,wx1, wy0,wy1}
                float4 q1 = w1q4[2 * p + 1];     // {wz0,wz1, b0, b1}
                float2v wx2 = {q0.x, q0.y};
                float2v wy2 = {q0.z, q0.w};
                float2v wz2 = {q1.x, q1.y};
                float2v bb2 = {q1.z, q1.w};
                float2v wsp = {ws2r[2 * p], ws2r[2 * p + 1]};
                #pragma unroll
                for (int tm = 0; tm < 2; ++tm) {
                    int tg = ph * 2 + tm;
                    float2v h2 = bb2;
                    h2 = __builtin_elementwise_fma((float2v){cxs[tg], cxs[tg]}, wx2, h2);
                    h2 = __builtin_elementwise_fma((float2v){cys[tg], cys[tg]}, wy2, h2);
                    h2 = __builtin_elementwise_fma((float2v){czs[tg], czs[tg]}, wz2, h2);
                    h2 = __builtin_elementwise_max(h2, (float2v){0.0f, 0.0f});
                    sig2[tm] = __builtin_elementwise_fma(h2, wsp, sig2[tm]);
                    packed[tm][p] = cvt_pk_bf16(h2[0], h2[1]);
                }
            }
            short8 Ah[2];
            #pragma unroll
            for (int tm = 0; tm < 2; ++tm) {
                uint4 v4 = {packed[tm][0], packed[tm][1], packed[tm][2], packed[tm][3]};
                Ah[tm] = __builtin_bit_cast(short8, v4);
            }
            const int bbase = (kc * 4) * 512 + lane * 8;
            #pragma unroll
            for (int tn = 0; tn < 4; ++tn) {
                short8 bh = *(const short8*)(bhiP + bbase + tn * 512);
                #pragma unroll
                for (int tm = 0; tm < 2; ++tm)
                    acc[tm][tn] = __builtin_amdgcn_mfma_f32_16x16x32_bf16(Ah[tm], bh, acc[tm][tn], 0, 0, 0);
            }
        }

        // phase C for this pass: feat rows -> fh, sigma partials collapse
        #pragma unroll
        for (int tm = 0; tm < 2; ++tm)
            #pragma unroll
            for (int tn = 0; tn < 4; ++tn)
                #pragma unroll
                for (int pr = 0; pr < 2; ++pr) {
                    uint32_t u = cvt_pk_bf16(acc[tm][tn][2 * pr], acc[tm][tn][2 * pr + 1]);
                    int n  = tn * 16 + c;
                    int m0 = mbase + (ph * 2 + tm) * 16 + q * 4 + 2 * pr;
                    int m1 = m0 + 1;
                    int i0 = m0 * 64 + (((n >> 3) ^ (m0 & 7)) << 3) + (n & 7);
                    int i1 = m1 * 64 + (((n >> 3) ^ (m1 & 7)) << 3) + (n & 7);
                    fh[i0] = (unsigned short)u;
                    fh[i1] = (unsigned short)(u >> 16);
                }
        #pragma unroll
        for (int tm = 0; tm < 2; ++tm) {
            float s = sig2[tm][0] + sig2[tm][1];
            s += __shfl_xor(s, 16);
            s += __shfl_xor(s, 32);
            sig[ph * 2 + tm] = s;
        }
    }

    {
        float b2s = *(const float*)(ws + WS_B2S);
        if (q == 0) {
            #pragma unroll
            for (int tm = 0; tm < 4; ++tm) {
                int m = mbase + tm * 16 + c;
                float sa = sig[tm] + b2s;
                float sg = (maskLds[m] > 0.5f)
                         ? (fmaxf(sa, 0.0f) + __logf(1.0f + __expf(-fabsf(sa)))) : 0.0f;
                aLds[m] = -sg * distLds[m];
            }
        }
    }
    __builtin_amdgcn_wave_barrier();

    // hd[] uniform loads hoisted: latency hides under the scan below
    float hd[4];
    #pragma unroll
    for (int tn = 0; tn < 4; ++tn) {
        int n = tn * 16 + c;
        hd[tn] = r_b1[n] + dxv * r_w1[64 * 64 + n] + dyv * r_w1[65 * 64 + n] + dzv * r_w1[66 * 64 + n];
    }

    // ---------------- transmittance scan -------------------------------------
    float av = aLds[tid];
    float v = av;
    #pragma unroll
    for (int off = 1; off < 64; off <<= 1) {
        float u2 = __shfl_up(v, off);
        if (lane >= off) v += u2;
    }
    if (lane == 63) sWaveSum[wv] = v;
    __syncthreads();
    float basev = 0.0f;
    #pragma unroll
    for (int w = 0; w < 4; ++w) basev += (w < wv) ? sWaveSum[w] : 0.0f;
    float excl = __shfl_up(v, 1);
    if (lane == 0) excl = 0.0f;
    float cum    = basev + excl;
    float trans  = __expf(cum);
    float weight = trans * (1.0f - __expf(av));
    bool  mask2  = maskA && (trans > 1e-4f);

    // ---------------- Phase D: rgb-hidden GEMM, two tm-passes (unroll 2) -----
    const unsigned short* __restrict__ rwP = (const unsigned short*)(ws + WS_RW1);

    #pragma unroll
    for (int ph = 0; ph < 2; ++ph) {
        // pass-0 epilogue writes rows mbase+0..31; pass-1 afr reads rows
        // mbase+32..63 -- disjoint, wave-private: safe under unroll.
        short8 afr[2][2];
        #pragma unroll
        for (int tm = 0; tm < 2; ++tm)
            #pragma unroll
            for (int ks = 0; ks < 2; ++ks) {
                int m = mbase + (ph * 2 + tm) * 16 + c;
                int gl = ks * 4 + q;
                afr[tm][ks] = *(const short8*)&fh[m * 64 + ((gl ^ (m & 7)) << 3)];
            }

        floatx4 acc[2][4];
        #pragma unroll
        for (int tm = 0; tm < 2; ++tm)
            #pragma unroll
            for (int tn = 0; tn < 4; ++tn) {
                floatx4 z; z[0] = 0.0f; z[1] = 0.0f; z[2] = 0.0f; z[3] = 0.0f;
                acc[tm][tn] = z;
            }
        #pragma unroll
        for (int ks = 0; ks < 2; ++ks)
            #pragma unroll
            for (int tn = 0; tn < 4; ++tn) {
                short8 rb = *(const short8*)(rwP + ((ks * 4 + tn) * 64 + lane) * 8);
                #pragma unroll
                for (int tm = 0; tm < 2; ++tm)
                    acc[tm][tn] = __builtin_amdgcn_mfma_f32_16x16x32_bf16(afr[tm][ks], rb, acc[tm][tn], 0, 0, 0);
            }

        __builtin_amdgcn_wave_barrier();
        #pragma unroll
        for (int tm = 0; tm < 2; ++tm)
            #pragma unroll
            for (int tn = 0; tn < 4; ++tn)
                #pragma unroll
                for (int pr = 0; pr < 2; ++pr) {
                    float2v a2 = {acc[tm][tn][2 * pr], acc[tm][tn][2 * pr + 1]};
                    a2 = a2 + (float2v){hd[tn], hd[tn]};
                    a2 = __builtin_elementwise_max(a2, (float2v){0.0f, 0.0f});
                    uint32_t u = cvt_pk_bf16(a2[0], a2[1]);
                    int n  = tn * 16 + c;
                    int m0 = mbase + (ph * 2 + tm) * 16 + q * 4 + 2 * pr;
                    int m1 = m0 + 1;
                    int i0 = m0 * 64 + (((n >> 3) ^ (m0 & 7)) << 3) + (n & 7);
                    int i1 = m1 * 64 + (((n >> 3) ^ (m1 & 7)) << 3) + (n & 7);
                    fh[i0] = (unsigned short)u;
                    fh[i1] = (unsigned short)(u >> 16);
                }
    }
    __builtin_amdgcn_wave_barrier();

    // ---------------- Phase E: final 64->3 via transposed MFMA ---------------
    aLds[tid] = mask2 ? weight : 0.0f;   // aLds life 2: weight*mask2
    __builtin_amdgcn_wave_barrier();

    const unsigned short* __restrict__ w2eP = (const unsigned short*)(ws + WS_W2E);
    short8 w2f[2];
    w2f[0] = *(const short8*)(w2eP + (0 * 64 + lane) * 8);
    w2f[1] = *(const short8*)(w2eP + (1 * 64 + lane) * 8);

    floatx4 eacc[4];
    #pragma unroll
    for (int tn = 0; tn < 4; ++tn) {
        floatx4 z; z[0] = 0.0f; z[1] = 0.0f; z[2] = 0.0f; z[3] = 0.0f;
        eacc[tn] = z;
    }
    #pragma unroll
    for (int kf = 0; kf < 2; ++kf)
        #pragma unroll
        for (int tn = 0; tn < 4; ++tn) {
            int m = mbase + tn * 16 + c;
            int gl = kf * 4 + q;
            short8 hb = *(const short8*)&fh[m * 64 + ((gl ^ (m & 7)) << 3)];
            eacc[tn] = __builtin_amdgcn_mfma_f32_16x16x32_bf16(w2f[kf], hb, eacc[tn], 0, 0, 0);
        }

    float r = 0.0f, g = 0.0f, b = 0.0f;
    if (q == 0) {
        float rb0 = r_b2[0], rb1 = r_b2[1], rb2v = r_b2[2];
        #pragma unroll
        for (int tn = 0; tn < 4; ++tn) {
            int m = mbase + tn * 16 + c;
            float wgt = aLds[m];
            r += wgt / (1.0f + __expf(-(eacc[tn][0] + rb0)));
            g += wgt / (1.0f + __expf(-(eacc[tn][1] + rb1)));
            b += wgt / (1.0f + __expf(-(eacc[tn][2] + rb2v)));
        }
    }
    #pragma unroll
    for (int off = 8; off > 0; off >>= 1) {
        r += __shfl_xor(r, off);
        g += __shfl_xor(g, off);
        b += __shfl_xor(b, off);
    }
    if (lane == 0) { sPart[wv][0] = r; sPart[wv][1] = g; sPart[wv][2] = b; }
    __syncthreads();
    if (tid == 0) {
        out[ray * 3 + 0] = sPart[0][0] + sPart[1][0] + sPart[2][0] + sPart[3][0];
        out[ray * 3 + 1] = sPart[0][1] + sPart[1][1] + sPart[2][1] + sPart[3][1];
        out[ray * 3 + 2] = sPart[0][2] + sPart[1][2] + sPart[2][2] + sPart[3][2];
    }
}

extern "C" void kernel_launch(void* const* d_in, const int* in_sizes, int n_in,
                              void* d_out, int out_size, void* d_ws, size_t ws_size,
                              hipStream_t stream) {
    const int n_rays = in_sizes[0] / 3;   // 4096
    nerf_prep<<<1, 256, 0, stream>>>(
        (const float*)d_in[3], (const float*)d_in[4], (const float*)d_in[5],
        (const float*)d_in[6], (const float*)d_in[7], (const float*)d_in[8],
        (const float*)d_in[9], (const float*)d_in[11], (unsigned char*)d_ws);
    nerf_mfma<<<n_rays, 256, 0, stream>>>(
        (const float*)d_in[0],  (const float*)d_in[1],  (const float*)d_in[2],
        (const float*)d_in[6],  (const float*)d_in[9],  (const float*)d_in[10],
        (const float*)d_in[12],
        (const unsigned char*)d_ws, (float*)d_out);
}

// Round 17
// 174.919 us; speedup vs baseline: 3.7742x; 3.7742x over previous
//
#include <hip/hip_runtime.h>
#include <hip/hip_bf16.h>
#include <math.h>
#include <stdint.h>

#define S    256
#define GN   128

typedef __attribute__((ext_vector_type(8))) short  short8;   // 8 bf16
typedef __attribute__((ext_vector_type(4))) float  floatx4;  // MFMA C/D
typedef __attribute__((ext_vector_type(2))) float  float2v;  // v_pk_*_f32 pair

// workspace layout (bytes)
#define WS_BHI 0          // ushort[4*4*64*8] = 16384 B  (f_w2 bf16, frag order)
#define WS_RW1 16384      // ushort[2*4*64*8] =  8192 B  (r_w1 bf16, frag order)
#define WS_B2S 24576      // float  (b2.s_w + s_b)
#define WS_WS2 24592      // float[128]  (W2 @ s_w, fp32)
#define WS_W1P 25104      // float[64*8] pair-interleaved layer-1 = 2048 B
#define WS_W2E 27152      // ushort[2*64*8] = 2048 B (r_w2^T bf16, A-frag order)

__device__ __forceinline__ unsigned short bf16_rtne(float f) {
    uint32_t u = __builtin_bit_cast(uint32_t, f);
    uint32_t r = (u + 0x7fffu + ((u >> 16) & 1u)) >> 16;
    return (unsigned short)r;
}
__device__ __forceinline__ uint32_t cvt_pk_bf16(float a, float b) {
    float2 hh; hh.x = a; hh.y = b;
    __hip_bfloat162 pk = __float22bfloat162_rn(hh);   // v_cvt_pk_bf16_f32
    uint32_t u; __builtin_memcpy(&u, &pk, 4);
    return u;
}

// ---------- pre-pack kernel: weights -> bf16 in MFMA fragment order ----------
__global__ __launch_bounds__(256)
void nerf_prep(const float* __restrict__ f_w1, const float* __restrict__ f_b1,
               const float* __restrict__ f_w2, const float* __restrict__ f_b2,
               const float* __restrict__ s_w,  const float* __restrict__ s_b,
               const float* __restrict__ r_w1, const float* __restrict__ r_w2,
               unsigned char* __restrict__ ws)
{
    const int tid = threadIdx.x;
    if (tid < 128) {                       // ws2 = W2 @ s_w  (fp32) -> global
        float acc = 0.0f;
        for (int n = 0; n < 64; ++n) acc += f_w2[tid * 64 + n] * s_w[n];
        ((float*)(ws + WS_WS2))[tid] = acc;
    } else if (tid == 128) {               // b2s = b2 . s_w + s_b
        float acc = s_b[0];
        for (int n = 0; n < 64; ++n) acc += f_b2[n] * s_w[n];
        *(float*)(ws + WS_B2S) = acc;
    }
    // layer-1 pair-interleaved pack: pair pp covers k=2pp,2pp+1:
    //   {wx0,wx1, wy0,wy1, wz0,wz1, b0,b1}  (aligned float2 pairs for v_pk_fma)
    {
        float* w1pk = (float*)(ws + WS_W1P);
        for (int pp = tid; pp < 64; pp += 256) {
            int k0 = 2 * pp, k1 = 2 * pp + 1;
            w1pk[pp * 8 + 0] = f_w1[k0];       w1pk[pp * 8 + 1] = f_w1[k1];
            w1pk[pp * 8 + 2] = f_w1[128 + k0]; w1pk[pp * 8 + 3] = f_w1[128 + k1];
            w1pk[pp * 8 + 4] = f_w1[256 + k0]; w1pk[pp * 8 + 5] = f_w1[256 + k1];
            w1pk[pp * 8 + 6] = f_b1[k0];       w1pk[pp * 8 + 7] = f_b1[k1];
        }
    }

    unsigned short* bhi = (unsigned short*)(ws + WS_BHI);
    for (int i = tid; i < 8192; i += 256) {
        int j = i & 7, L = (i >> 3) & 63, g = i >> 9;   // g = kc*4 + tn
        int tn = g & 3, kc = g >> 2;
        int q = L >> 4, cc = L & 15;
        int k = kc * 32 + q * 8 + j;
        bhi[i] = bf16_rtne(f_w2[k * 64 + tn * 16 + cc]);
    }
    unsigned short* rw = (unsigned short*)(ws + WS_RW1);
    for (int i = tid; i < 4096; i += 256) {
        int j = i & 7, L = (i >> 3) & 63, g = i >> 9;   // g = ks*4 + tn
        int tn = g & 3, ks = g >> 2;
        int q = L >> 4, cc = L & 15;
        int k = ks * 32 + q * 8 + j;
        rw[i] = bf16_rtne(r_w1[k * 64 + tn * 16 + cc]);
    }
    // r_w2^T in A-fragment order for the phase-E MFMA:
    // A[row=out-channel][k=hidden]; rows 3..15 zero.
    unsigned short* w2e = (unsigned short*)(ws + WS_W2E);
    for (int i = tid; i < 1024; i += 256) {
        int j = i & 7, L = (i >> 3) & 63, kf = i >> 9;
        int q = L >> 4, ch = L & 15;
        int k = kf * 32 + q * 8 + j;
        w2e[i] = (ch < 3) ? bf16_rtne(r_w2[k * 3 + ch]) : (unsigned short)0;
    }
}

// ---------------------------- main kernel -----------------------------------
// R17 = exact R15 revert (kc unroll 2, phase-D ph unroll 1) + hd[] hoist.
// R16 lesson: at the (256,4) 128-reg cap, full kc unroll + phase-D unroll 2
// needs ~200 live ranges -> ~1 KB/thread scratch spill, 2.2 GB HBM traffic,
// 6x regression. Unroll depth 2 is the ceiling at this register budget.
__global__ __launch_bounds__(256, 4)
void nerf_mfma(const float* __restrict__ rays_o,
               const float* __restrict__ rays_d,
               const float* __restrict__ grid,
               const float* __restrict__ f_b2,
               const float* __restrict__ r_w1,
               const float* __restrict__ r_b1,
               const float* __restrict__ r_b2,
               const unsigned char* __restrict__ ws,
               float* __restrict__ out)
{
    // fh: bf16 [256 rows][64], XOR-swizzled in 8-ushort groups: conflict-free b128
    __shared__ unsigned short fh[256 * 64];
    __shared__ float w1p[512];            // pair-interleaved layer-1
    __shared__ float ws2L[128];           // W2 @ s_w (fp32)
    __shared__ float aLds[S];             // life 1: alpha for scan; life 2: weight*mask2
    __shared__ float maskLds[S];
    __shared__ float distLds[S];
    __shared__ float sWaveSum[4];
    __shared__ float sPart[4][3];

    const int tid   = threadIdx.x;
    const int ray   = blockIdx.x;
    const int lane  = tid & 63;
    const int wv    = tid >> 6;
    const int q     = lane >> 4;
    const int c     = lane & 15;
    const int mbase = wv * 64;

    // stage layer-1 pack (2 KB) + ws2 (512 B) into LDS
    if (tid < 128) {
        ((float4*)w1p)[tid] = ((const float4*)(ws + WS_W1P))[tid];
        ws2L[tid] = ((const float*)(ws + WS_WS2))[tid];
    }

    // ---------------- Phase A: geometry + grid sample (thread = sample) ------
    const float stop = 1.0f - 1.0f / (float)(S + 2);
    const float step = stop / (float)S;
    float u0 = (float)tid * step;
    float u1 = (float)(tid + 1) * step;
    float t    = (u0 < 0.5f) ? 2.0f * u0 : 1.0f / (2.0f - 2.0f * u0);
    float tn_  = (u1 < 0.5f) ? 2.0f * u1 : 1.0f / (2.0f - 2.0f * u1);
    float dist = tn_ - t;

    float ox = rays_o[ray * 3 + 0], oy = rays_o[ray * 3 + 1], oz = rays_o[ray * 3 + 2];
    float dxv = rays_d[ray * 3 + 0], dyv = rays_d[ray * 3 + 1], dzv = rays_d[ray * 3 + 2];

    float px = ox + dxv * t, py = oy + dyv * t, pz = oz + dzv * t;
    float nrm = sqrtf(px * px + py * py + pz * pz);
    float scale = (nrm <= 1.0f) ? 0.5f : (2.0f - 1.0f / nrm) / nrm * 0.5f;
    float cx = px * scale, cy = py * scale, cz = pz * scale;

    float ix = ((cx + 1.0f) * (float)GN - 1.0f) * 0.5f;
    float iy = ((cy + 1.0f) * (float)GN - 1.0f) * 0.5f;
    float iz = ((cz + 1.0f) * (float)GN - 1.0f) * 0.5f;
    float fx0 = floorf(ix), fy0 = floorf(iy), fz0 = floorf(iz);
    float fx = ix - fx0, fy = iy - fy0, fz = iz - fz0;
    int x0 = (int)fx0, y0 = (int)fy0, z0 = (int)fz0;

    float occ = 0.0f;
    #pragma unroll
    for (int dzc = 0; dzc < 2; ++dzc)
    #pragma unroll
    for (int dyc = 0; dyc < 2; ++dyc)
    #pragma unroll
    for (int dxc = 0; dxc < 2; ++dxc) {
        int xc = x0 + dxc, yc = y0 + dyc, zc = z0 + dzc;
        float w = (dxc ? fx : 1.0f - fx) * (dyc ? fy : 1.0f - fy) * (dzc ? fz : 1.0f - fz);
        if (xc >= 0 && xc < GN && yc >= 0 && yc < GN && zc >= 0 && zc < GN)
            occ += w * grid[(zc * GN + yc) * GN + xc];
    }
    bool maskA = occ > 0.01f;
    maskLds[tid] = maskA ? 1.0f : 0.0f;
    distLds[tid] = dist;

    // coords of the A-fragment rows this thread covers (intra-wave broadcast)
    float cxs[4], cys[4], czs[4];
    #pragma unroll
    for (int tm = 0; tm < 4; ++tm) {
        int src = tm * 16 + c;
        cxs[tm] = __shfl(cx, src, 64);
        cys[tm] = __shfl(cy, src, 64);
        czs[tm] = __shfl(cz, src, 64);
    }
    __syncthreads();   // w1p / ws2L staged

    // ------- Phase B+C: feat GEMM in two tm-passes (acc[2][4] = 32 AGPR) -----
    const unsigned short* __restrict__ bhiP = (const unsigned short*)(ws + WS_BHI);
    float sig[4];

    #pragma unroll 1
    for (int ph = 0; ph < 2; ++ph) {
        floatx4 acc[2][4];
        {
            float b2v[4];
            #pragma unroll
            for (int tn = 0; tn < 4; ++tn) b2v[tn] = f_b2[tn * 16 + c];
            #pragma unroll
            for (int tm = 0; tm < 2; ++tm)
                #pragma unroll
                for (int tn = 0; tn < 4; ++tn) {
                    floatx4 v; v[0] = b2v[tn]; v[1] = b2v[tn]; v[2] = b2v[tn]; v[3] = b2v[tn];
                    acc[tm][tn] = v;
                }
        }
        float2v sig2[2];
        sig2[0][0] = 0.0f; sig2[0][1] = 0.0f;
        sig2[1][0] = 0.0f; sig2[1][1] = 0.0f;

        #pragma unroll 2
        for (int kc = 0; kc < 4; ++kc) {
            const int k0  = kc * 32 + q * 8;
            const int pp0 = kc * 16 + q * 4;
            const float4* __restrict__ w1q4 = (const float4*)&w1p[pp0 * 8];
            float ws2r[8];
            *(float4*)(ws2r)     = *(const float4*)&ws2L[k0];
            *(float4*)(ws2r + 4) = *(const float4*)&ws2L[k0 + 4];

            uint32_t packed[2][4];
            #pragma unroll
            for (int p = 0; p < 4; ++p) {
                float4 q0 = w1q4[2 * p];         // {wx0,wx1, wy0,wy1}
                float4 q1 = w1q4[2 * p + 1];     // {wz0,wz1, b0, b1}
                float2v wx2 = {q0.x, q0.y};
                float2v wy2 = {q0.z, q0.w};
                float2v wz2 = {q1.x, q1.y};
                float2v bb2 = {q1.z, q1.w};
                float2v wsp = {ws2r[2 * p], ws2r[2 * p + 1]};
                #pragma unroll
                for (int tm = 0; tm < 2; ++tm) {
                    int tg = ph * 2 + tm;
                    float2v h2 = bb2;
                    h2 = __builtin_elementwise_fma((float2v){cxs[tg], cxs[tg]}, wx2, h2);
                    h2 = __builtin_elementwise_fma((float2v){cys[tg], cys[tg]}, wy2, h2);
                    h2 = __builtin_elementwise_fma((float2v){czs[tg], czs[tg]}, wz2, h2);
                    h2 = __builtin_elementwise_max(h2, (float2v){0.0f, 0.0f});
                    sig2[tm] = __builtin_elementwise_fma(h2, wsp, sig2[tm]);
                    packed[tm][p] = cvt_pk_bf16(h2[0], h2[1]);
                }
            }
            short8 Ah[2];
            #pragma unroll
            for (int tm = 0; tm < 2; ++tm) {
                uint4 v4 = {packed[tm][0], packed[tm][1], packed[tm][2], packed[tm][3]};
                Ah[tm] = __builtin_bit_cast(short8, v4);
            }
            const int bbase = (kc * 4) * 512 + lane * 8;
            #pragma unroll
            for (int tn = 0; tn < 4; ++tn) {
                short8 bh = *(const short8*)(bhiP + bbase + tn * 512);
                #pragma unroll
                for (int tm = 0; tm < 2; ++tm)
                    acc[tm][tn] = __builtin_amdgcn_mfma_f32_16x16x32_bf16(Ah[tm], bh, acc[tm][tn], 0, 0, 0);
            }
        }

        // phase C for this pass: feat rows -> fh, sigma partials collapse
        #pragma unroll
        for (int tm = 0; tm < 2; ++tm)
            #pragma unroll
            for (int tn = 0; tn < 4; ++tn)
                #pragma unroll
                for (int pr = 0; pr < 2; ++pr) {
                    uint32_t u = cvt_pk_bf16(acc[tm][tn][2 * pr], acc[tm][tn][2 * pr + 1]);
                    int n  = tn * 16 + c;
                    int m0 = mbase + (ph * 2 + tm) * 16 + q * 4 + 2 * pr;
                    int m1 = m0 + 1;
                    int i0 = m0 * 64 + (((n >> 3) ^ (m0 & 7)) << 3) + (n & 7);
                    int i1 = m1 * 64 + (((n >> 3) ^ (m1 & 7)) << 3) + (n & 7);
                    fh[i0] = (unsigned short)u;
                    fh[i1] = (unsigned short)(u >> 16);
                }
        #pragma unroll
        for (int tm = 0; tm < 2; ++tm) {
            float s = sig2[tm][0] + sig2[tm][1];
            s += __shfl_xor(s, 16);
            s += __shfl_xor(s, 32);
            sig[ph * 2 + tm] = s;
        }
    }

    {
        float b2s = *(const float*)(ws + WS_B2S);
        if (q == 0) {
            #pragma unroll
            for (int tm = 0; tm < 4; ++tm) {
                int m = mbase + tm * 16 + c;
                float sa = sig[tm] + b2s;
                float sg = (maskLds[m] > 0.5f)
                         ? (fmaxf(sa, 0.0f) + __logf(1.0f + __expf(-fabsf(sa)))) : 0.0f;
                aLds[m] = -sg * distLds[m];
            }
        }
    }
    __builtin_amdgcn_wave_barrier();

    // hd[] uniform loads hoisted: latency hides under the scan below
    float hd[4];
    #pragma unroll
    for (int tn = 0; tn < 4; ++tn) {
        int n = tn * 16 + c;
        hd[tn] = r_b1[n] + dxv * r_w1[64 * 64 + n] + dyv * r_w1[65 * 64 + n] + dzv * r_w1[66 * 64 + n];
    }

    // ---------------- transmittance scan -------------------------------------
    float av = aLds[tid];
    float v = av;
    #pragma unroll
    for (int off = 1; off < 64; off <<= 1) {
        float u2 = __shfl_up(v, off);
        if (lane >= off) v += u2;
    }
    if (lane == 63) sWaveSum[wv] = v;
    __syncthreads();
    float basev = 0.0f;
    #pragma unroll
    for (int w = 0; w < 4; ++w) basev += (w < wv) ? sWaveSum[w] : 0.0f;
    float excl = __shfl_up(v, 1);
    if (lane == 0) excl = 0.0f;
    float cum    = basev + excl;
    float trans  = __expf(cum);
    float weight = trans * (1.0f - __expf(av));
    bool  mask2  = maskA && (trans > 1e-4f);

    // ---------------- Phase D: rgb-hidden GEMM, two tm-passes ----------------
    const unsigned short* __restrict__ rwP = (const unsigned short*)(ws + WS_RW1);

    #pragma unroll 1
    for (int ph = 0; ph < 2; ++ph) {
        // pass-0 epilogue writes rows mbase+0..31; pass-1 afr reads rows
        // mbase+32..63 -- disjoint, wave-private: no barrier needed.
        short8 afr[2][2];
        #pragma unroll
        for (int tm = 0; tm < 2; ++tm)
            #pragma unroll
            for (int ks = 0; ks < 2; ++ks) {
                int m = mbase + (ph * 2 + tm) * 16 + c;
                int gl = ks * 4 + q;
                afr[tm][ks] = *(const short8*)&fh[m * 64 + ((gl ^ (m & 7)) << 3)];
            }

        floatx4 acc[2][4];
        #pragma unroll
        for (int tm = 0; tm < 2; ++tm)
            #pragma unroll
            for (int tn = 0; tn < 4; ++tn) {
                floatx4 z; z[0] = 0.0f; z[1] = 0.0f; z[2] = 0.0f; z[3] = 0.0f;
                acc[tm][tn] = z;
            }
        #pragma unroll
        for (int ks = 0; ks < 2; ++ks)
            #pragma unroll
            for (int tn = 0; tn < 4; ++tn) {
                short8 rb = *(const short8*)(rwP + ((ks * 4 + tn) * 64 + lane) * 8);
                #pragma unroll
                for (int tm = 0; tm < 2; ++tm)
                    acc[tm][tn] = __builtin_amdgcn_mfma_f32_16x16x32_bf16(afr[tm][ks], rb, acc[tm][tn], 0, 0, 0);
            }

        __builtin_amdgcn_wave_barrier();
        #pragma unroll
        for (int tm = 0; tm < 2; ++tm)
            #pragma unroll
            for (int tn = 0; tn < 4; ++tn)
                #pragma unroll
                for (int pr = 0; pr < 2; ++pr) {
                    float2v a2 = {acc[tm][tn][2 * pr], acc[tm][tn][2 * pr + 1]};
                    a2 = a2 + (float2v){hd[tn], hd[tn]};
                    a2 = __builtin_elementwise_max(a2, (float2v){0.0f, 0.0f});
                    uint32_t u = cvt_pk_bf16(a2[0], a2[1]);
                    int n  = tn * 16 + c;
                    int m0 = mbase + (ph * 2 + tm) * 16 + q * 4 + 2 * pr;
                    int m1 = m0 + 1;
                    int i0 = m0 * 64 + (((n >> 3) ^ (m0 & 7)) << 3) + (n & 7);
                    int i1 = m1 * 64 + (((n >> 3) ^ (m1 & 7)) << 3) + (n & 7);
                    fh[i0] = (unsigned short)u;
                    fh[i1] = (unsigned short)(u >> 16);
                }
    }
    __builtin_amdgcn_wave_barrier();

    // ---------------- Phase E: final 64->3 via transposed MFMA ---------------
    aLds[tid] = mask2 ? weight : 0.0f;   // aLds life 2: weight*mask2
    __builtin_amdgcn_wave_barrier();

    const unsigned short* __restrict__ w2eP = (const unsigned short*)(ws + WS_W2E);
    short8 w2f[2];
    w2f[0] = *(const short8*)(w2eP + (0 * 64 + lane) * 8);
    w2f[1] = *(const short8*)(w2eP + (1 * 64 + lane) * 8);

    floatx4 eacc[4];
    #pragma unroll
    for (int tn = 0; tn < 4; ++tn) {
        floatx4 z; z[0] = 0.0f; z[1] = 0.0f; z[2] = 0.0f; z[3] = 0.0f;
        eacc[tn] = z;
    }
    #pragma unroll
    for (int kf = 0; kf < 2; ++kf)
        #pragma unroll
        for (int tn = 0; tn < 4; ++tn) {
            int m = mbase + tn * 16 + c;
            int gl = kf * 4 + q;
            short8 hb = *(const short8*)&fh[m * 64 + ((gl ^ (m & 7)) << 3)];
            eacc[tn] = __builtin_amdgcn_mfma_f32_16x16x32_bf16(w2f[kf], hb, eacc[tn], 0, 0, 0);
        }

    float r = 0.0f, g = 0.0f, b = 0.0f;
    if (q == 0) {
        float rb0 = r_b2[0], rb1 = r_b2[1], rb2v = r_b2[2];
        #pragma unroll
        for (int tn = 0; tn < 4; ++tn) {
            int m = mbase + tn * 16 + c;
            float wgt = aLds[m];
            r += wgt / (1.0f + __expf(-(eacc[tn][0] + rb0)));
            g += wgt / (1.0f + __expf(-(eacc[tn][1] + rb1)));
            b += wgt / (1.0f + __expf(-(eacc[tn][2] + rb2v)));
        }
    }
    #pragma unroll
    for (int off = 8; off > 0; off >>= 1) {
        r += __shfl_xor(r, off);
        g += __shfl_xor(g, off);
        b += __shfl_xor(b, off);
    }
    if (lane == 0) { sPart[wv][0] = r; sPart[wv][1] = g; sPart[wv][2] = b; }
    __syncthreads();
    if (tid == 0) {
        out[ray * 3 + 0] = sPart[0][0] + sPart[1][0] + sPart[2][0] + sPart[3][0];
        out[ray * 3 + 1] = sPart[0][1] + sPart[1][1] + sPart[2][1] + sPart[3][1];
        out[ray * 3 + 2] = sPart[0][2] + sPart[1][2] + sPart[2][2] + sPart[3][2];
    }
}

extern "C" void kernel_launch(void* const* d_in, const int* in_sizes, int n_in,
                              void* d_out, int out_size, void* d_ws, size_t ws_size,
                              hipStream_t stream) {
    const int n_rays = in_sizes[0] / 3;   // 4096
    nerf_prep<<<1, 256, 0, stream>>>(
        (const float*)d_in[3], (const float*)d_in[4], (const float*)d_in[5],
        (const float*)d_in[6], (const float*)d_in[7], (const float*)d_in[8],
        (const float*)d_in[9], (const float*)d_in[11], (unsigned char*)d_ws);
    nerf_mfma<<<n_rays, 256, 0, stream>>>(
        (const float*)d_in[0],  (const float*)d_in[1],  (const float*)d_in[2],
        (const float*)d_in[6],  (const float*)d_in[9],  (const float*)d_in[10],
        (const float*)d_in[12],
        (const unsigned char*)d_ws, (float*)d_out);
}